// Round 14
// baseline (587.786 us; speedup 1.0000x reference)
//
#include <hip/hip_runtime.h>
#include <hip/hip_cooperative_groups.h>
#include <math.h>
#include <float.h>

namespace cg = cooperative_groups;

constexpr int B  = 4;
constexpr int N  = 3072;
constexpr int C  = 512;
constexpr int CL = 768;

typedef unsigned short u16;
typedef __attribute__((ext_vector_type(8))) short s16x8;
typedef __attribute__((ext_vector_type(4))) float f32x4;

// ---------------- JAX threefry2x32 (exact) ----------------
__device__ __forceinline__ unsigned rotl32(unsigned v, int d) { return (v << d) | (v >> (32 - d)); }

__device__ inline void threefry2x32(unsigned k0, unsigned k1, unsigned c0, unsigned c1,
                                    unsigned& o0, unsigned& o1) {
  unsigned ks0 = k0, ks1 = k1, ks2 = 0x1BD11BDAu ^ k0 ^ k1;
  unsigned x0 = c0 + ks0, x1 = c1 + ks1;
#define TF_RND(r) { x0 += x1; x1 = rotl32(x1, (r)); x1 ^= x0; }
  TF_RND(13) TF_RND(15) TF_RND(26) TF_RND(6)  x0 += ks1; x1 += ks2 + 1u;
  TF_RND(17) TF_RND(29) TF_RND(16) TF_RND(24) x0 += ks2; x1 += ks0 + 2u;
  TF_RND(13) TF_RND(15) TF_RND(26) TF_RND(6)  x0 += ks0; x1 += ks1 + 3u;
  TF_RND(17) TF_RND(29) TF_RND(16) TF_RND(24) x0 += ks1; x1 += ks2 + 4u;
  TF_RND(13) TF_RND(15) TF_RND(26) TF_RND(6)  x0 += ks2; x1 += ks0 + 5u;
#undef TF_RND
  o0 = x0; o1 = x1;
}

__device__ inline float jax_uniform_bn(int f) {
  constexpr int HALF = (B * N) / 2;
  unsigned o0, o1, bits;
  if (f < HALF) { threefry2x32(0u, 42u, (unsigned)f, (unsigned)(f + HALF), o0, o1); bits = o0; }
  else          { threefry2x32(0u, 42u, (unsigned)(f - HALF), (unsigned)f, o0, o1); bits = o1; }
  return __uint_as_float((bits >> 9) | 0x3f800000u) - 1.0f;
}

// ---------------- bf16 split helpers ----------------
__device__ __forceinline__ u16 bf16rn(float f) {
  unsigned u = __float_as_uint(f);
  unsigned r = u + 0x7FFFu + ((u >> 16) & 1u);
  return (u16)(r >> 16);
}
__device__ __forceinline__ float bf16tof(u16 h) {
  return __uint_as_float(((unsigned)h) << 16);
}

// ---------------- prep: sq + hi/lo split + init (one wave per row) ----------------
__global__ __launch_bounds__(64) void k_prep(const float* __restrict__ x, float* __restrict__ sq,
                                             u16* __restrict__ xhi, u16* __restrict__ xlo,
                                             int* __restrict__ counts,
                                             unsigned long long* __restrict__ packed) {
  int row = blockIdx.x;   // 0..B*N-1
  int lane = threadIdx.x;
  const float* xr = x + (size_t)row * C;
  u16* hr = xhi + (size_t)row * C;
  u16* lr = xlo + (size_t)row * C;
  float s = 0.f;
  for (int c = lane * 4; c < C; c += 256) {
    float4 v = *(const float4*)(xr + c);
    s += v.x * v.x + v.y * v.y + v.z * v.z + v.w * v.w;
    u16 h0 = bf16rn(v.x), h1 = bf16rn(v.y), h2 = bf16rn(v.z), h3 = bf16rn(v.w);
    u16 l0 = bf16rn(v.x - bf16tof(h0));
    u16 l1 = bf16rn(v.y - bf16tof(h1));
    u16 l2 = bf16rn(v.z - bf16tof(h2));
    u16 l3 = bf16rn(v.w - bf16tof(h3));
    uint2 hp, lp;
    hp.x = (unsigned)h0 | ((unsigned)h1 << 16); hp.y = (unsigned)h2 | ((unsigned)h3 << 16);
    lp.x = (unsigned)l0 | ((unsigned)l1 << 16); lp.y = (unsigned)l2 | ((unsigned)l3 << 16);
    *(uint2*)(hr + c) = hp;
    *(uint2*)(lr + c) = lp;
  }
  for (int o = 32; o > 0; o >>= 1) s += __shfl_down(s, o, 64);
  if (lane == 0) {
    sq[row] = s;
    packed[row] = ~0ull;
    if (row < B * CL) counts[row] = 0;
  }
}

// ---------------- branchless sorted-insert of v into ascending t[0..4] ----------------
__device__ __forceinline__ void ins5b(float t[5], float v) {
  float c = v;
  float n;
  n = fminf(t[0], c); c = fmaxf(t[0], c); t[0] = n;
  n = fminf(t[1], c); c = fmaxf(t[1], c); t[1] = n;
  n = fminf(t[2], c); c = fmaxf(t[2], c); t[2] = n;
  n = fminf(t[3], c); c = fmaxf(t[3], c); t[3] = n;
  t[4] = fminf(t[4], c);
}

constexpr int NT3 = N / 128;                   // 24
constexpr int NTILE3 = NT3 * (NT3 + 1) / 2;    // 300

// ---------------- dist GEMM (3-term bf16 MFMA), 128x128 tile (round-13 proven) ----------------
__global__ __launch_bounds__(256, 3) void k_distm(const u16* __restrict__ xhi, const u16* __restrict__ xlo,
                                                  const float* __restrict__ sq,
                                                  float* __restrict__ distbuf,
                                                  float* __restrict__ part5, int b0) {
  constexpr int ASTR = 40;
  __shared__ __align__(16) char smem[40960];
  u16* sAh = (u16*)smem;
  u16* sAl = sAh + 128 * ASTR;
  u16* sBh = sAl + 128 * ASTR;
  u16* sBl = sBh + 128 * ASTR;

  int bl = blockIdx.y, b = b0 + bl;
  int idx = blockIdx.x;
  int ti = 0, rem = idx;
  while (rem >= NT3 - ti) { rem -= NT3 - ti; ++ti; }
  int tj = ti + rem;
  int i0 = ti * 128, j0 = tj * 128;
  bool do_mirror = (ti != tj);

  const float* sqb = sq + (size_t)b * N;
  float* dist = distbuf + (size_t)bl * N * N;

  int tid = threadIdx.x;
  int srow = tid >> 1, shalf = (tid & 1) * 16;
  const u16* gAh = xhi + ((size_t)b * N + i0 + srow) * C + shalf;
  const u16* gAl = xlo + ((size_t)b * N + i0 + srow) * C + shalf;
  const u16* gBh = xhi + ((size_t)b * N + j0 + srow) * C + shalf;
  const u16* gBl = xlo + ((size_t)b * N + j0 + srow) * C + shalf;
  int wofs = srow * ASTR + shalf;

  int lane = tid & 63, w = tid >> 6;
  int wr = (w >> 1) * 64, wc = (w & 1) * 64;
  int l15 = lane & 15, l4 = lane >> 4;

  f32x4 acc[4][4];
#pragma unroll
  for (int rt = 0; rt < 4; ++rt)
#pragma unroll
    for (int ct = 0; ct < 4; ++ct)
#pragma unroll
      for (int e = 0; e < 4; ++e) acc[rt][ct][e] = 0.f;

  uint4 p0 = *(const uint4*)gAh, p1 = *(const uint4*)(gAh + 8);
  uint4 p2 = *(const uint4*)gAl, p3 = *(const uint4*)(gAl + 8);
  uint4 p4 = *(const uint4*)gBh, p5 = *(const uint4*)(gBh + 8);
  uint4 p6 = *(const uint4*)gBl, p7 = *(const uint4*)(gBl + 8);

  for (int k0 = 0; k0 < C; k0 += 32) {
    *(uint4*)&sAh[wofs] = p0; *(uint4*)&sAh[wofs + 8] = p1;
    *(uint4*)&sAl[wofs] = p2; *(uint4*)&sAl[wofs + 8] = p3;
    *(uint4*)&sBh[wofs] = p4; *(uint4*)&sBh[wofs + 8] = p5;
    *(uint4*)&sBl[wofs] = p6; *(uint4*)&sBl[wofs + 8] = p7;
    __syncthreads();
    int kn = k0 + 32;
    if (kn < C) {
      p0 = *(const uint4*)(gAh + kn); p1 = *(const uint4*)(gAh + kn + 8);
      p2 = *(const uint4*)(gAl + kn); p3 = *(const uint4*)(gAl + kn + 8);
      p4 = *(const uint4*)(gBh + kn); p5 = *(const uint4*)(gBh + kn + 8);
      p6 = *(const uint4*)(gBl + kn); p7 = *(const uint4*)(gBl + kn + 8);
    }
    s16x8 ah[4], al[4];
#pragma unroll
    for (int rt = 0; rt < 4; ++rt) {
      int ro = (wr + rt * 16 + l15) * ASTR + l4 * 8;
      ah[rt] = *(const s16x8*)&sAh[ro];
      al[rt] = *(const s16x8*)&sAl[ro];
    }
#pragma unroll
    for (int ct = 0; ct < 4; ++ct) {
      int co = (wc + ct * 16 + l15) * ASTR + l4 * 8;
      s16x8 bh = *(const s16x8*)&sBh[co];
      s16x8 bl = *(const s16x8*)&sBl[co];
#pragma unroll
      for (int rt = 0; rt < 4; ++rt) {
        acc[rt][ct] = __builtin_amdgcn_mfma_f32_16x16x32_bf16(ah[rt], bh, acc[rt][ct], 0, 0, 0);
        acc[rt][ct] = __builtin_amdgcn_mfma_f32_16x16x32_bf16(ah[rt], bl, acc[rt][ct], 0, 0, 0);
        acc[rt][ct] = __builtin_amdgcn_mfma_f32_16x16x32_bf16(al[rt], bh, acc[rt][ct], 0, 0, 0);
      }
    }
    __syncthreads();   // also guards smem reuse by the epilogue below
  }

  const float SQC = 22.627416997969522f;
  float sqi[4][4], sqj[4];
#pragma unroll
  for (int rt = 0; rt < 4; ++rt)
#pragma unroll
    for (int r = 0; r < 4; ++r) sqi[rt][r] = sqb[i0 + wr + rt * 16 + l4 * 4 + r];
#pragma unroll
  for (int ct = 0; ct < 4; ++ct) sqj[ct] = sqb[j0 + wc + ct * 16 + l15];

#pragma unroll
  for (int rt = 0; rt < 4; ++rt)
#pragma unroll
    for (int ct = 0; ct < 4; ++ct)
#pragma unroll
      for (int r = 0; r < 4; ++r) {
        float d2 = fmaxf(sqi[rt][r] + sqj[ct] - 2.0f * acc[rt][ct][r], 0.0f);
        acc[rt][ct][r] = sqrtf(d2) / SQC;
      }

  constexpr int TSTR = 76;
  float* sT = (float*)smem + w * (32 * TSTR);

  float t5A[5] = {FLT_MAX, FLT_MAX, FLT_MAX, FLT_MAX, FLT_MAX};
  float mxA = 0.f;

#pragma unroll
  for (int p = 0; p < 2; ++p) {
#pragma unroll
    for (int cth = 0; cth < 2; ++cth) {
      int ct = p * 2 + cth;
      int cl = cth * 16 + l15;
#pragma unroll
      for (int rt = 0; rt < 4; ++rt)
#pragma unroll
        for (int r = 0; r < 4; ++r)
          sT[cl * TSTR + rt * 16 + l4 * 4 + r] = acc[rt][ct][r];
    }
    // direct write
    {
      int g4 = lane & 7, rbase = lane >> 3;
#pragma unroll
      for (int it = 0; it < 8; ++it) {
        int rl = it * 8 + rbase;
        float4 v = make_float4(sT[(4 * g4 + 0) * TSTR + rl],
                               sT[(4 * g4 + 1) * TSTR + rl],
                               sT[(4 * g4 + 2) * TSTR + rl],
                               sT[(4 * g4 + 3) * TSTR + rl]);
        *(float4*)(dist + (size_t)(i0 + wr + rl) * N + j0 + wc + p * 32 + 4 * g4) = v;
      }
    }
    // mirror write
    if (do_mirror) {
      int cg = lane >> 4, rq = lane & 15;
#pragma unroll
      for (int cc = 0; cc < 8; ++cc) {
        int c = cc * 4 + cg;
        float4 v = *(const float4*)&sT[c * TSTR + rq * 4];
        *(float4*)(dist + (size_t)(j0 + wc + p * 32 + c) * N + i0 + wr + rq * 4) = v;
      }
    }
    // A-side partial scan
    for (int c = 0; c < 32; ++c) {
      float v = sT[c * TSTR + lane];
      mxA = fmaxf(mxA, v);
      ins5b(t5A, v);
    }
    // mirror-side partials
    if (do_mirror) {
      int cl = lane & 31, half = lane >> 5;
      float t5B[5] = {FLT_MAX, FLT_MAX, FLT_MAX, FLT_MAX, FLT_MAX};
      float mxB = 0.f;
      for (int k = 0; k < 32; ++k) {
        float v = sT[cl * TSTR + half * 32 + k];
        mxB = fmaxf(mxB, v);
        ins5b(t5B, v);
      }
      mxB = fmaxf(mxB, __shfl_xor(mxB, 32, 64));
      float o0 = __shfl_xor(t5B[0], 32, 64);
      float o1 = __shfl_xor(t5B[1], 32, 64);
      float o2 = __shfl_xor(t5B[2], 32, 64);
      float o3 = __shfl_xor(t5B[3], 32, 64);
      float o4 = __shfl_xor(t5B[4], 32, 64);
      ins5b(t5B, o0); ins5b(t5B, o1); ins5b(t5B, o2); ins5b(t5B, o3); ins5b(t5B, o4);
      if (half == 0) {
        int rowB = j0 + wc + p * 32 + cl;
        int slotB = ti * 2 + (wr >> 6);
        float* dst = part5 + (((size_t)bl * 48 + slotB) * 6) * N + rowB;
        dst[0] = t5B[0]; dst[(size_t)N] = t5B[1]; dst[2 * (size_t)N] = t5B[2];
        dst[3 * (size_t)N] = t5B[3]; dst[4 * (size_t)N] = t5B[4]; dst[5 * (size_t)N] = mxB;
      }
    }
  }
  {
    int rowA = i0 + wr + lane;
    int slotA = tj * 2 + (wc >> 6);
    float* dst = part5 + (((size_t)bl * 48 + slotA) * 6) * N + rowA;
    dst[0] = t5A[0]; dst[(size_t)N] = t5A[1]; dst[2 * (size_t)N] = t5A[2];
    dst[3 * (size_t)N] = t5A[3]; dst[4 * (size_t)N] = t5A[4]; dst[5 * (size_t)N] = mxA;
  }
}

// ---------------- cooperative tail: dens->dmax->maskmin->rank->assign->fin->scan->fill->gather+final ----------------
struct TailArgs {
  const float* part5;
  float* density;
  float* rowmax;
  float* distmax;
  const float* distbuf;
  float* score;
  int* index_down;
  int* rank;
  unsigned long long* packed;
  int* idx_cluster;
  int* counts;
  int* offsets;
  int* cursor;
  int* members;
  const float* x;
  const int* idx_token;
  const float* agg_weight;
  float* out0;
  float* out1;
  float* out2;
  float* out3;
};

constexpr int TGRID = 256;   // one block per CU: co-residency guaranteed

__global__ __launch_bounds__(256) void k_tail(TailArgs a) {
  cg::grid_group grid = cg::this_grid();
  __shared__ float smf[N];        // 12 KB phase-shared buffer
  __shared__ float sred[16];
  int tid = threadIdx.x;
  int wv = tid >> 6, lane = tid & 63;
  int gtid = blockIdx.x * 256 + tid;

  // ---- Phase 1: density + rowmax from part5 ----
  for (int g = gtid; g < B * N; g += TGRID * 256) {
    int b = g / N, r = g % N;
    const float* base = a.part5 + (size_t)b * 48 * 6 * N + r;
    float t5[5] = {FLT_MAX, FLT_MAX, FLT_MAX, FLT_MAX, FLT_MAX};
    float mx = 0.f;
    for (int s = 0; s < 48; ++s) {
      const float* sp = base + (size_t)s * 6 * N;
      ins5b(t5, sp[0]);
      ins5b(t5, sp[(size_t)N]);
      ins5b(t5, sp[2 * (size_t)N]);
      ins5b(t5, sp[3 * (size_t)N]);
      ins5b(t5, sp[4 * (size_t)N]);
      mx = fmaxf(mx, sp[5 * (size_t)N]);
    }
    float sum = t5[0] * t5[0] + t5[1] * t5[1] + t5[2] * t5[2] + t5[3] * t5[3] + t5[4] * t5[4];
    a.density[g] = expf(-(sum / 5.0f)) + jax_uniform_bn(g) * 1e-6f;
    a.rowmax[g] = mx;
  }
  grid.sync();

  // ---- Phase 2: distmax[b] (blocks 0..3) ----
  if (blockIdx.x < B) {
    int b = blockIdx.x;
    float mx = 0.f;
    for (int j = tid; j < N; j += 256) mx = fmaxf(mx, a.rowmax[b * N + j]);
#pragma unroll
    for (int m = 1; m < 64; m <<= 1) mx = fmaxf(mx, __shfl_xor(mx, m, 64));
    if (lane == 0) sred[wv] = mx;
    __syncthreads();
    if (tid == 0)
      a.distmax[b] = fmaxf(fmaxf(sred[0], sred[1]), fmaxf(sred[2], sred[3]));
  }
  grid.sync();

  // ---- Phase 3: masked min -> score (64 blocks/batch, 48 rows/block, 12 rows/wave) ----
  {
    int b = blockIdx.x >> 6;
    int blk = blockIdx.x & 63;
    const float* db = a.density + (size_t)b * N;
    for (int j = tid * 4; j < N; j += 1024) *(float4*)(smf + j) = *(const float4*)(db + j);
    __syncthreads();
    float dmax = a.distmax[b];
    for (int t = 0; t < 12; ++t) {
      int r = blk * 48 + wv * 12 + t;
      float di = smf[r];
      const float* row = a.distbuf + (size_t)b * N * N + (size_t)r * N;
      float mn = dmax;
#pragma unroll
      for (int it = 0; it < N / 256; ++it) {
        int j = it * 256 + lane * 4;
        float4 v = *(const float4*)(row + j);
        float4 d = *(const float4*)(smf + j);
        mn = fminf(mn, (d.x > di) ? v.x : dmax);
        mn = fminf(mn, (d.y > di) ? v.y : dmax);
        mn = fminf(mn, (d.z > di) ? v.z : dmax);
        mn = fminf(mn, (d.w > di) ? v.w : dmax);
      }
#pragma unroll
      for (int m = 1; m < 64; m <<= 1) mn = fminf(mn, __shfl_xor(mn, m, 64));
      if (lane == 0) a.score[b * N + r] = mn * di;
    }
  }
  grid.sync();

  // ---- Phase 4: counting-rank top-CL ----
  {
    int b = blockIdx.x >> 6;
    int blk = blockIdx.x & 63;
    const float* sb = a.score + (size_t)b * N;
    for (int j = tid * 4; j < N; j += 1024) *(float4*)(smf + j) = *(const float4*)(sb + j);
    __syncthreads();
    for (int t = 0; t < 12; ++t) {
      int i = blk * 48 + wv * 12 + t;
      float si = smf[i];
      int cnt = 0;
#pragma unroll
      for (int it = 0; it < N / 256; ++it) {
        int j = it * 256 + lane * 4;
        float4 v = *(const float4*)(smf + j);
        cnt += (v.x > si) || (v.x == si && (j + 0) < i);
        cnt += (v.y > si) || (v.y == si && (j + 1) < i);
        cnt += (v.z > si) || (v.z == si && (j + 2) < i);
        cnt += (v.w > si) || (v.w == si && (j + 3) < i);
      }
#pragma unroll
      for (int m = 1; m < 64; m <<= 1) cnt += __shfl_xor(cnt, m, 64);
      if (lane == 0) {
        a.rank[b * N + i] = (cnt < CL) ? cnt : -1;
        if (cnt < CL) a.index_down[b * CL + cnt] = i;
      }
    }
  }
  grid.sync();

  // ---- Phase 5: assignment (units: b(4) x rchunk(8) x jblk(12) = 384) ----
  {
    int* ssid = (int*)smf;
    for (int u = blockIdx.x; u < 384; u += TGRID) {
      int b = u / 96, rem2 = u % 96, rch = rem2 / 12, jb = rem2 % 12;
      __syncthreads();
      if (tid < 96) ssid[tid] = a.index_down[b * CL + rch * 96 + tid];
      __syncthreads();
      int j = jb * 256 + tid;
      const float* base = a.distbuf + (size_t)b * N * N;
      float best = FLT_MAX; int bestr = 0;
#pragma unroll 8
      for (int r = 0; r < 96; ++r) {
        float d = base[(size_t)ssid[r] * N + j];
        if (d < best) { best = d; bestr = rch * 96 + r; }
      }
      unsigned long long key = ((unsigned long long)__float_as_uint(best) << 32) | (unsigned)bestr;
      atomicMin(&a.packed[(size_t)b * N + j], key);
    }
  }
  grid.sync();

  // ---- Phase 6: final assignment + histogram ----
  for (int g = gtid; g < B * N; g += TGRID * 256) {
    int b = g / N;
    int r = a.rank[g];
    int cl = (r >= 0) ? r : (int)(unsigned)(a.packed[g] & 0xffffffffull);
    a.idx_cluster[g] = cl;
    atomicAdd(&a.counts[b * CL + cl], 1);
  }
  grid.sync();

  // ---- Phase 7: exclusive scan of counts (block 0) ----
  if (blockIdx.x == 0) {
    int* sm = (int*)smf;
    constexpr int T = B * CL;  // 3072
    for (int p = tid; p < T; p += 256) sm[p] = a.counts[p];
    __syncthreads();
    for (int off = 1; off < T; off <<= 1) {
      int v[12]; int n = 0;
      for (int p = tid; p < T; p += 256) { v[n++] = (p >= off) ? sm[p - off] : 0; }
      __syncthreads();
      n = 0;
      for (int p = tid; p < T; p += 256) { sm[p] += v[n++]; }
      __syncthreads();
    }
    for (int p = tid; p < T; p += 256) {
      int e = sm[p] - a.counts[p];
      a.offsets[p] = e; a.cursor[p] = e;
    }
  }
  grid.sync();

  // ---- Phase 8: fill member lists ----
  for (int g = gtid; g < B * N; g += TGRID * 256) {
    int b = g / N, i = g % N;
    int seg = b * CL + a.idx_cluster[g];
    int pos = atomicAdd(&a.cursor[seg], 1);
    a.members[pos] = i;
  }
  grid.sync();

  // ---- Phase 9a: gather (2 segs per block per iter; 512 segs/iter x 6) ----
  for (int it = 0; it < 6; ++it) {
    int seg = blockIdx.x * 2 + (tid >> 7) + it * 512;
    int b = seg / CL;
    int cnt = a.counts[seg], off = a.offsets[seg];
    float nw = 1.0f / ((float)cnt + 1e-6f);
    int c = (tid & 127) * 4;
    const float* xb = a.x + (size_t)b * N * C;
    float4 accv = make_float4(0.f, 0.f, 0.f, 0.f);
    for (int m = 0; m < cnt; ++m) {
      int tok = a.members[off + m];
      float4 v = *(const float4*)(xb + (size_t)tok * C + c);
      accv.x += v.x * nw; accv.y += v.y * nw; accv.z += v.z * nw; accv.w += v.w * nw;
    }
    *(float4*)(a.out0 + (size_t)seg * C + c) = accv;
  }

  // ---- Phase 9b: final outputs (no dep on gather) ----
  for (int g = gtid; g < B * N; g += TGRID * 256) {
    int b = g / N;
    int it = a.idx_token[g];
    int clt = a.idx_cluster[b * N + it];
    float nwt = 1.0f / ((float)a.counts[b * CL + clt] + 1e-6f);
    a.out1[g] = a.agg_weight[g] * nwt;
    a.out2[g] = (float)clt;
    a.out3[g] = (float)a.idx_cluster[g];
  }
}

// ---------------- launch ----------------
extern "C" void kernel_launch(void* const* d_in, const int* in_sizes, int n_in,
                              void* d_out, int out_size, void* d_ws, size_t ws_size,
                              hipStream_t stream) {
  const float* x          = (const float*)d_in[0];
  const int*   idx_token  = (const int*)d_in[1];
  const float* agg_weight = (const float*)d_in[2];

  float* out0 = (float*)d_out;
  float* out1 = out0 + (size_t)B * CL * C;
  float* out2 = out1 + (size_t)B * N;
  float* out3 = out2 + (size_t)B * N;

  char* w = (char*)d_ws;
  auto carve = [&](size_t bytes) { char* p = w; w += (bytes + 255) & ~(size_t)255; return p; };
  float*    sq         = (float*)carve((size_t)B * N * 4);
  float*    density    = (float*)carve((size_t)B * N * 4);
  float*    score      = (float*)carve((size_t)B * N * 4);
  float*    rowmax     = (float*)carve((size_t)B * N * 4);
  float*    distmax    = (float*)carve((size_t)B * 4);
  int*      index_down = (int*)carve((size_t)B * CL * 4);
  int*      rank       = (int*)carve((size_t)B * N * 4);
  int*      idx_clus   = (int*)carve((size_t)B * N * 4);
  int*      counts     = (int*)carve((size_t)B * CL * 4);
  int*      offsets    = (int*)carve((size_t)B * CL * 4);
  int*      cursor     = (int*)carve((size_t)B * CL * 4);
  int*      members    = (int*)carve((size_t)B * N * 4);
  unsigned long long* packed = (unsigned long long*)carve((size_t)B * N * 8);
  u16*      xhi        = (u16*)carve((size_t)B * N * C * 2);
  u16*      xlo        = (u16*)carve((size_t)B * N * C * 2);
  float*    part5      = (float*)carve((size_t)B * 48 * 6 * N * 4);
  float*    distbuf    = (float*)w;   // 4 x N*N*4 = 604 MB (ws verified in prior rounds)

  k_prep<<<B * N, 64, 0, stream>>>(x, sq, xhi, xlo, counts, packed);
  k_distm<<<dim3(NTILE3, B), 256, 0, stream>>>(xhi, xlo, sq, distbuf, part5, 0);

  TailArgs ta;
  ta.part5 = part5; ta.density = density; ta.rowmax = rowmax; ta.distmax = distmax;
  ta.distbuf = distbuf; ta.score = score; ta.index_down = index_down; ta.rank = rank;
  ta.packed = packed; ta.idx_cluster = idx_clus; ta.counts = counts; ta.offsets = offsets;
  ta.cursor = cursor; ta.members = members; ta.x = x; ta.idx_token = idx_token;
  ta.agg_weight = agg_weight; ta.out0 = out0; ta.out1 = out1; ta.out2 = out2; ta.out3 = out3;
  void* kargs[] = { (void*)&ta };
  hipLaunchCooperativeKernel((const void*)k_tail, dim3(TGRID), dim3(256), kargs, 0, stream);
}